// Round 8
// baseline (135.578 us; speedup 1.0000x reference)
//
#include <hip/hip_runtime.h>
#include <stdint.h>

typedef __attribute__((ext_vector_type(8))) short short8v;
typedef __attribute__((ext_vector_type(4))) float float4v;

__device__ __forceinline__ unsigned short f32_to_bf16(float f) {
    union { float f; uint32_t u; } v; v.f = f;
    uint32_t u = v.u;
    u += 0x7FFFu + ((u >> 16) & 1u);
    return (unsigned short)(u >> 16);
}
__device__ __forceinline__ float bf16_to_f32(unsigned short s) {
    union { uint32_t u; float f; } v; v.u = ((uint32_t)s) << 16;
    return v.f;
}

#define T_LEN 4096
#define C_DIM 1024
#define HSZ 64

// ---------------- kernel 0: W -> Wt (bf16, transposed [192][1024]) ----------------
__global__ void wt_kernel(const float* __restrict__ Wq, const float* __restrict__ Wk,
                          const float* __restrict__ Wv, unsigned short* __restrict__ Wt) {
    int tid = blockIdx.x * blockDim.x + threadIdx.x;   // 0 .. 3*65536-1
    int m   = tid >> 16;
    int rem = tid & 65535;
    int kk  = rem >> 6;
    int col = rem & 63;
    const float* W = (m == 0) ? Wq : ((m == 1) ? Wk : Wv);
    Wt[(size_t)m * 65536 + (size_t)col * 1024 + kk] = f32_to_bf16(W[(size_t)kk * 64 + col]);
}

// ---------------- kernel 1: fused QKV projection (8 waves, split-K) ----------------
// q, k written [B*T][64] row-major; v written TRANSPOSED: vT[b][d][t]
#define XLD 1032   // 1024 + 8 pad

__global__ __launch_bounds__(512) void qkv_kernel(
    const float* __restrict__ x, const unsigned short* __restrict__ Wt,
    unsigned short* __restrict__ qo, unsigned short* __restrict__ ko,
    unsigned short* __restrict__ vto)
{
    __shared__ __align__(16) unsigned short xs[16 * XLD];   // 33 KB; aliased by part[] later
    const int tid  = threadIdx.x;
    const int row0 = blockIdx.x * 16;

    #pragma unroll
    for (int i = 0; i < 8; ++i) {
        int f   = i * 512 + tid;           // float4 index, 4096 total
        int row = f >> 8, c4 = f & 255;
        const float4 val = *((const float4*)x + (size_t)(row0 + row) * 256 + c4);
        union { unsigned short s[4]; uint64_t u; } pk;
        pk.s[0] = f32_to_bf16(val.x); pk.s[1] = f32_to_bf16(val.y);
        pk.s[2] = f32_to_bf16(val.z); pk.s[3] = f32_to_bf16(val.w);
        *(uint64_t*)(&xs[row * XLD + c4 * 4]) = pk.u;
    }
    __syncthreads();

    const int wave = tid >> 6, lane = tid & 63;
    const int wq = wave & 3, wh = wave >> 2;     // wq: output triple, wh: K-half
    const int g = lane >> 4, c = lane & 15;

    float4v acc0 = {0,0,0,0}, acc1 = {0,0,0,0}, acc2 = {0,0,0,0};
    #pragma unroll 4
    for (int ks = wh * 16; ks < wh * 16 + 16; ++ks) {
        const int koff = ks * 32 + g * 8;
        short8v a  = *(const short8v*)(&xs[c * XLD + koff]);
        short8v b0 = *(const short8v*)(&Wt[(size_t)((wq*3+0)*16 + c) * 1024 + koff]);
        short8v b1 = *(const short8v*)(&Wt[(size_t)((wq*3+1)*16 + c) * 1024 + koff]);
        short8v b2 = *(const short8v*)(&Wt[(size_t)((wq*3+2)*16 + c) * 1024 + koff]);
        acc0 = __builtin_amdgcn_mfma_f32_16x16x32_bf16(a, b0, acc0, 0, 0, 0);
        acc1 = __builtin_amdgcn_mfma_f32_16x16x32_bf16(a, b1, acc1, 0, 0, 0);
        acc2 = __builtin_amdgcn_mfma_f32_16x16x32_bf16(a, b2, acc2, 0, 0, 0);
    }

    // combine K-halves through LDS (aliased over xs; xs reads are done)
    float* part = (float*)xs;   // [4 wq][3][64 lanes][4] = 12 KB
    __syncthreads();
    float4v accs[3] = {acc0, acc1, acc2};
    if (wh == 1) {
        #pragma unroll
        for (int t = 0; t < 3; ++t)
            #pragma unroll
            for (int j = 0; j < 4; ++j)
                part[((wq * 3 + t) * 64 + lane) * 4 + j] = accs[t][j];
    }
    __syncthreads();
    if (wh == 0) {
        #pragma unroll
        for (int t = 0; t < 3; ++t) {
            #pragma unroll
            for (int j = 0; j < 4; ++j)
                accs[t][j] += part[((wq * 3 + t) * 64 + lane) * 4 + j];
            int ct = wq * 3 + t;
            int m = ct >> 2, hcol = (ct & 3) * 16 + c;
            if (m == 2) {
                #pragma unroll
                for (int j = 0; j < 4; ++j) {
                    int r = row0 + g * 4 + j;
                    vto[((size_t)(r >> 12) * 64 + hcol) * 4096 + (r & 4095)] = f32_to_bf16(accs[t][j]);
                }
            } else {
                unsigned short* dst = (m == 0) ? qo : ko;
                float sc = (m == 0) ? 0.125f : 1.0f;   // fold 1/sqrt(64) into q
                #pragma unroll
                for (int j = 0; j < 4; ++j)
                    dst[(size_t)(row0 + g * 4 + j) * 64 + hcol] = f32_to_bf16(accs[t][j] * sc);
            }
        }
    }
}

// ---------------- kernel 2: causal flash attention (kv-split, partials) ----------------
// 2048 blocks = (qb desc, batch, h16, kvh). Block owns 16 q-rows and HALF the
// KV tile range; 8 waves slice its range mod 8. Writes unnormalized partials
// (M, L, O bf16) to ws; merge_kernel combines the two halves.
#define PLD 72

__global__ __launch_bounds__(512) void attn_kernel(
    const unsigned short* __restrict__ qi, const unsigned short* __restrict__ ki,
    const unsigned short* __restrict__ vt,
    unsigned short* __restrict__ pO, float* __restrict__ pM, float* __restrict__ pL)
{
    __shared__ __align__(16) unsigned short Ps[8][16 * PLD];   // per-wave P buffer
    __shared__ unsigned short CombO[7][16][64];                // bf16 partial O
    __shared__ float CombM[7][16];
    __shared__ float CombL[7][16];

    const int tid  = threadIdx.x;
    const int wave = tid >> 6, lane = tid & 63;
    const int g = lane >> 4, c = lane & 15;

    const int bid   = (int)blockIdx.x;
    const int qb    = 127 - (bid >> 4);       // LPT: longest first
    const int sub   = bid & 15;
    const int batch = sub & 3;
    const int h16   = (sub >> 2) & 1;
    const int kvh   = (sub >> 3) & 1;
    const int rbase = qb * 32 + h16 * 16;
    const size_t bo = (size_t)batch * T_LEN * HSZ;
    const int pidx  = ((qb * 4 + batch) * 2 + h16) * 2 + kvh;

    const int nt  = ((rbase + 15) >> 6) + 1;
    const int nth = (nt + 1) >> 1;
    const int lo  = kvh * nth;
    const int hi  = (nt < lo + nth) ? nt : (lo + nth);

    short8v qf0 = *(const short8v*)(qi + bo + (size_t)(rbase + c) * 64 +  0 + g * 8);
    short8v qf1 = *(const short8v*)(qi + bo + (size_t)(rbase + c) * 64 + 32 + g * 8);

    float4v acc[4];
    #pragma unroll
    for (int i = 0; i < 4; ++i) acc[i] = (float4v){0,0,0,0};
    float mrow[4] = {-3e38f, -3e38f, -3e38f, -3e38f};
    float lsum[4] = {0.f, 0.f, 0.f, 0.f};

    unsigned short* Pw = &Ps[wave][0];

    for (int t = lo + wave; t < hi; t += 8) {
        const int s0 = t * 64;

        // ---- S = Q K^T : B-frags straight from global K (L2-resident) ----
        float4v sa[4];
        #pragma unroll
        for (int ct = 0; ct < 4; ++ct) {
            const unsigned short* krow = ki + bo + (size_t)(s0 + ct * 16 + c) * 64;
            short8v b0 = *(const short8v*)(krow +  0 + g * 8);
            short8v b1 = *(const short8v*)(krow + 32 + g * 8);
            float4v z = {0, 0, 0, 0};
            z = __builtin_amdgcn_mfma_f32_16x16x32_bf16(qf0, b0, z, 0, 0, 0);
            sa[ct] = __builtin_amdgcn_mfma_f32_16x16x32_bf16(qf1, b1, z, 0, 0, 0);
        }

        // ---- issue first half of vT B-frags (latency hides under softmax) ----
        short8v vf0[4];
        #pragma unroll
        for (int ct = 0; ct < 4; ++ct)
            vf0[ct] = *(const short8v*)(vt + bo + (size_t)(ct * 16 + c) * 4096 + s0 + 0 + g * 8);

        // ---- causal mask ----
        if (s0 + 63 > rbase) {
            #pragma unroll
            for (int ct = 0; ct < 4; ++ct)
                #pragma unroll
                for (int j = 0; j < 4; ++j)
                    if (s0 + ct * 16 + c > rbase + g * 4 + j) sa[ct][j] = -3e38f;
        }

        // ---- online softmax (cross-lane sum deferred) ----
        #pragma unroll
        for (int j = 0; j < 4; ++j) {
            float mx = fmaxf(fmaxf(sa[0][j], sa[1][j]), fmaxf(sa[2][j], sa[3][j]));
            #pragma unroll
            for (int sh = 1; sh < 16; sh <<= 1) mx = fmaxf(mx, __shfl_xor(mx, sh, 64));
            const float nm = fmaxf(mrow[j], mx);
            const float al = __expf(mrow[j] - nm);
            mrow[j] = nm;
            float ps = 0.f;
            #pragma unroll
            for (int ct = 0; ct < 4; ++ct) {
                float p = __expf(sa[ct][j] - nm);
                sa[ct][j] = p;
                ps += p;
            }
            lsum[j] = lsum[j] * al + ps;
            #pragma unroll
            for (int ct = 0; ct < 4; ++ct) acc[ct][j] *= al;
        }

        // ---- P (D-layout) -> per-wave LDS -> A-fragment layout ----
        #pragma unroll
        for (int ct = 0; ct < 4; ++ct)
            #pragma unroll
            for (int j = 0; j < 4; ++j)
                Pw[(g * 4 + j) * PLD + ct * 16 + c] = f32_to_bf16(sa[ct][j]);

        // ---- second half of vT B-frags (hides under P roundtrip) ----
        short8v vf1[4];
        #pragma unroll
        for (int ct = 0; ct < 4; ++ct)
            vf1[ct] = *(const short8v*)(vt + bo + (size_t)(ct * 16 + c) * 4096 + s0 + 32 + g * 8);

        short8v pa0 = *(const short8v*)(&Pw[c * PLD +  0 + g * 8]);
        short8v pa1 = *(const short8v*)(&Pw[c * PLD + 32 + g * 8]);

        // ---- O += P V ----
        #pragma unroll
        for (int ct = 0; ct < 4; ++ct)
            acc[ct] = __builtin_amdgcn_mfma_f32_16x16x32_bf16(pa0, vf0[ct], acc[ct], 0, 0, 0);
        #pragma unroll
        for (int ct = 0; ct < 4; ++ct)
            acc[ct] = __builtin_amdgcn_mfma_f32_16x16x32_bf16(pa1, vf1[ct], acc[ct], 0, 0, 0);
    }

    // ---- per-wave: reduce row sums across the 16 c-lanes ----
    #pragma unroll
    for (int j = 0; j < 4; ++j) {
        float l = lsum[j];
        #pragma unroll
        for (int sh = 1; sh < 16; sh <<= 1) l += __shfl_xor(l, sh, 64);
        lsum[j] = l;   // uniform across lanes
    }

    // ---- contributions: waves 1..7 -> LDS slot wave-1 (bf16 O, f32 m/l) ----
    if (wave != 0) {
        const int s = wave - 1;
        #pragma unroll
        for (int ct = 0; ct < 4; ++ct)
            #pragma unroll
            for (int j = 0; j < 4; ++j)
                CombO[s][g * 4 + j][ct * 16 + c] = f32_to_bf16(acc[ct][j]);
        if (c == 0) {
            #pragma unroll
            for (int j = 0; j < 4; ++j) {
                CombM[s][g * 4 + j] = mrow[j];
                CombL[s][g * 4 + j] = lsum[j];
            }
        }
    }
    __syncthreads();

    // ---- wave 0 combines slices, writes UNNORMALIZED partials ----
    if (wave == 0) {
        float a0[4], as[7][4], lt[4];
        #pragma unroll
        for (int j = 0; j < 4; ++j) {
            const int r = g * 4 + j;
            float M = mrow[j];
            #pragma unroll
            for (int s = 0; s < 7; ++s) M = fmaxf(M, CombM[s][r]);
            a0[j] = __expf(mrow[j] - M);
            lt[j] = lsum[j] * a0[j];
            #pragma unroll
            for (int s = 0; s < 7; ++s) {
                as[s][j] = __expf(CombM[s][r] - M);
                lt[j] += as[s][j] * CombL[s][r];
            }
            if (c == 0) {
                pM[pidx * 16 + r] = M;
                pL[pidx * 16 + r] = lt[j];
            }
        }
        #pragma unroll
        for (int ct = 0; ct < 4; ++ct)
            #pragma unroll
            for (int j = 0; j < 4; ++j) {
                const int r = g * 4 + j;
                float o = acc[ct][j] * a0[j];
                #pragma unroll
                for (int s = 0; s < 7; ++s)
                    o += as[s][j] * bf16_to_f32(CombO[s][r][ct * 16 + c]);
                pO[pidx * 1024 + r * 64 + ct * 16 + c] = f32_to_bf16(o);
            }
    }
}

// ---------------- kernel 3: merge the two kv-halves ----------------
__global__ __launch_bounds__(256) void merge_kernel(
    const unsigned short* __restrict__ pO, const float* __restrict__ pM,
    const float* __restrict__ pL, float* __restrict__ out)
{
    const int b = (int)blockIdx.x;          // = qb*8 + batch*2 + h16
    const int h16   = b & 1;
    const int batch = (b >> 1) & 3;
    const int qb    = b >> 3;
    const int rbase = qb * 32 + h16 * 16;
    const int pa = b * 2, pb = b * 2 + 1;

    #pragma unroll
    for (int k = 0; k < 4; ++k) {
        const int e = k * 256 + (int)threadIdx.x;   // 0..1023
        const int row = e >> 6, col = e & 63;
        const float Ma = pM[pa * 16 + row], Mb = pM[pb * 16 + row];
        const float La = pL[pa * 16 + row], Lb = pL[pb * 16 + row];
        const float M  = fmaxf(Ma, Mb);
        const float ea = __expf(Ma - M), eb = __expf(Mb - M);
        const float Oa = bf16_to_f32(pO[pa * 1024 + e]);
        const float Ob = bf16_to_f32(pO[pb * 1024 + e]);
        out[(size_t)batch * T_LEN * HSZ + (size_t)(rbase + row) * 64 + col] =
            (Oa * ea + Ob * eb) / (La * ea + Lb * eb);
    }
}

extern "C" void kernel_launch(void* const* d_in, const int* in_sizes, int n_in,
                              void* d_out, int out_size, void* d_ws, size_t ws_size,
                              hipStream_t stream) {
    const float* x  = (const float*)d_in[0];
    const float* Wq = (const float*)d_in[1];
    const float* Wk = (const float*)d_in[2];
    const float* Wv = (const float*)d_in[3];

    char* ws = (char*)d_ws;
    unsigned short* Wt = (unsigned short*)ws;                      // 384 KiB
    unsigned short* q  = (unsigned short*)(ws + 393216);           // 2 MiB
    unsigned short* k  = (unsigned short*)(ws + 2490368);          // 2 MiB
    unsigned short* vT = (unsigned short*)(ws + 4587520);          // 2 MiB
    unsigned short* pO = (unsigned short*)(ws + 6684672);          // 4 MiB (bf16)
    float* pM          = (float*)(ws + 10878976);                  // 128 KiB
    float* pL          = (float*)(ws + 11010048);                  // 128 KiB
    float* out = (float*)d_out;

    hipLaunchKernelGGL(wt_kernel,   dim3(768),  dim3(256), 0, stream, Wq, Wk, Wv, Wt);
    hipLaunchKernelGGL(qkv_kernel,  dim3(1024), dim3(512), 0, stream, x, Wt, q, k, vT);
    hipLaunchKernelGGL(attn_kernel, dim3(2048), dim3(512), 0, stream, q, k, vT, pO, pM, pL);
    hipLaunchKernelGGL(merge_kernel, dim3(1024), dim3(256), 0, stream, pO, pM, pL, out);
}

// Round 9
// 123.666 us; speedup vs baseline: 1.0963x; 1.0963x over previous
//
#include <hip/hip_runtime.h>
#include <stdint.h>

typedef __attribute__((ext_vector_type(8))) short short8v;
typedef __attribute__((ext_vector_type(4))) float float4v;

__device__ __forceinline__ unsigned short f32_to_bf16(float f) {
    union { float f; uint32_t u; } v; v.f = f;
    uint32_t u = v.u;
    u += 0x7FFFu + ((u >> 16) & 1u);
    return (unsigned short)(u >> 16);
}

#define T_LEN 4096
#define C_DIM 1024
#define HSZ 64

// ---------------- kernel 0: W -> Wt (bf16, transposed [192][1024]) ----------------
__global__ void wt_kernel(const float* __restrict__ Wq, const float* __restrict__ Wk,
                          const float* __restrict__ Wv, unsigned short* __restrict__ Wt) {
    int tid = blockIdx.x * blockDim.x + threadIdx.x;   // 0 .. 3*65536-1
    int m   = tid >> 16;
    int rem = tid & 65535;
    int kk  = rem >> 6;
    int col = rem & 63;
    const float* W = (m == 0) ? Wq : ((m == 1) ? Wk : Wv);
    Wt[(size_t)m * 65536 + (size_t)col * 1024 + kk] = f32_to_bf16(W[(size_t)kk * 64 + col]);
}

// ---------------- kernel 1: fused QKV projection ----------------
// q, k written [B*T][64] row-major; v written TRANSPOSED: vT[b][d][t].
// XCD pinning: bid%8 -> XCD; batch=(bid>>1)&3 so batch b is produced (and its
// q/k/vT write-allocated in L2) on XCDs {2b,2b+1}, where attn will read it.
#define XLD 1032   // 1024 + 8 pad

__global__ __launch_bounds__(256) void qkv_kernel(
    const float* __restrict__ x, const unsigned short* __restrict__ Wt,
    unsigned short* __restrict__ qo, unsigned short* __restrict__ ko,
    unsigned short* __restrict__ vto)
{
    __shared__ __align__(16) unsigned short xs[16 * XLD];
    const int tid = threadIdx.x;
    const int bid = (int)blockIdx.x;
    // rowidx in [0,1024): batch = (bid>>1)&3 (XCD-pinned), rest from high bits
    const int rowidx = (((bid >> 1) & 3) << 8) + ((bid >> 3) << 1) + (bid & 1);
    const int row0 = rowidx * 16;

    #pragma unroll
    for (int i = 0; i < 16; ++i) {
        int f   = i * 256 + tid;           // float4 index, 4096 total
        int row = f >> 8, c4 = f & 255;
        const float4 val = *((const float4*)x + (size_t)(row0 + row) * 256 + c4);
        union { unsigned short s[4]; uint64_t u; } pk;
        pk.s[0] = f32_to_bf16(val.x); pk.s[1] = f32_to_bf16(val.y);
        pk.s[2] = f32_to_bf16(val.z); pk.s[3] = f32_to_bf16(val.w);
        *(uint64_t*)(&xs[row * XLD + c4 * 4]) = pk.u;
    }
    __syncthreads();

    const int wave = tid >> 6, lane = tid & 63;
    const int g = lane >> 4, c = lane & 15;

    float4v acc0 = {0,0,0,0}, acc1 = {0,0,0,0}, acc2 = {0,0,0,0};
    #pragma unroll 4
    for (int ks = 0; ks < 32; ++ks) {
        const int koff = ks * 32 + g * 8;
        short8v a  = *(const short8v*)(&xs[c * XLD + koff]);
        short8v b0 = *(const short8v*)(&Wt[(size_t)((wave*3+0)*16 + c) * 1024 + koff]);
        short8v b1 = *(const short8v*)(&Wt[(size_t)((wave*3+1)*16 + c) * 1024 + koff]);
        short8v b2 = *(const short8v*)(&Wt[(size_t)((wave*3+2)*16 + c) * 1024 + koff]);
        acc0 = __builtin_amdgcn_mfma_f32_16x16x32_bf16(a, b0, acc0, 0, 0, 0);
        acc1 = __builtin_amdgcn_mfma_f32_16x16x32_bf16(a, b1, acc1, 0, 0, 0);
        acc2 = __builtin_amdgcn_mfma_f32_16x16x32_bf16(a, b2, acc2, 0, 0, 0);
    }

    float4v accs[3] = {acc0, acc1, acc2};
    #pragma unroll
    for (int t = 0; t < 3; ++t) {
        int ct = wave * 3 + t;
        int m = ct >> 2, hcol = (ct & 3) * 16 + c;
        if (m == 2) {
            // vT[b][hcol][t_global]
            #pragma unroll
            for (int j = 0; j < 4; ++j) {
                int r = row0 + g * 4 + j;
                vto[((size_t)(r >> 12) * 64 + hcol) * 4096 + (r & 4095)] = f32_to_bf16(accs[t][j]);
            }
        } else {
            unsigned short* dst = (m == 0) ? qo : ko;
            float sc = (m == 0) ? 0.125f : 1.0f;   // fold 1/sqrt(64) into q
            #pragma unroll
            for (int j = 0; j < 4; ++j)
                dst[(size_t)(row0 + g * 4 + j) * 64 + hcol] = f32_to_bf16(accs[t][j] * sc);
        }
    }
}

// ---------------- kernel 2: causal flash attention (R5 structure) ----------------
// 8 waves/block: wave = qh + 2*slice. Each (qh,slice) wave runs online softmax
// over tiles t ≡ slice (mod 4) of its 16 q-rows, directly from global (K/vT
// now XCD-L2-resident). Slices combined at the end via LDS.
// XCD pinning: batch = (bid>>1)&3 so XCDs {2b,2b+1} only touch batch b
// (per-XCD K+vT working set 1 MB < 4 MB L2). In-XCD complementary qb pairing
// (qb + 127-qb per CU slot) keeps CU work balanced.
#define PLD 72

__global__ __launch_bounds__(512) void attn_kernel(
    const unsigned short* __restrict__ qi, const unsigned short* __restrict__ ki,
    const unsigned short* __restrict__ vt, float* __restrict__ out)
{
    __shared__ __align__(16) unsigned short Ps[8][16 * PLD];  // per-wave P buffer
    __shared__ float CombO[6][16][64];                        // slices 1..3 x qh 0..1
    __shared__ float CombM[6][16];
    __shared__ float CombL[6][16];

    const int tid   = threadIdx.x;
    const int wave  = tid >> 6, lane = tid & 63;
    const int qh    = wave & 1, slice = wave >> 1;
    const int g = lane >> 4, c = lane & 15;

    const int bid   = (int)blockIdx.x;
    const int batch = (bid >> 1) & 3;     // bid%8 -> XCD; XCD pair {2b,2b+1} = batch b
    const int q0    = bid & 1;
    const int m     = bid >> 3;           // [0,64) per (batch,q0)
    const int mm    = m & 31;
    // complementary pairing within each XCD: slot mm gets qb, slot mm (2nd pass) 127-qb
    const int qb = q0 ? ((m < 32) ? 2 * mm + 1 : 126 - 2 * mm)
                      : ((m < 32) ? 2 * mm     : 127 - 2 * mm);

    const int rbase = qb * 32 + qh * 16;
    const size_t bo = (size_t)batch * T_LEN * HSZ;

    short8v qf0 = *(const short8v*)(qi + bo + (size_t)(rbase + c) * 64 +  0 + g * 8);
    short8v qf1 = *(const short8v*)(qi + bo + (size_t)(rbase + c) * 64 + 32 + g * 8);

    float4v acc[4];
    #pragma unroll
    for (int i2 = 0; i2 < 4; ++i2) acc[i2] = (float4v){0,0,0,0};
    float mrow[4] = {-3e38f, -3e38f, -3e38f, -3e38f};
    float lsum[4] = {0.f, 0.f, 0.f, 0.f};

    const int nt_w = ((rbase + 15) >> 6) + 1;   // tiles needed by this wave's rows
    unsigned short* Pw = &Ps[wave][0];

    for (int t = slice; t < nt_w; t += 4) {
        const int s0 = t * 64;

        // ---- S = Q K^T : B-frags straight from global K (L2-resident) ----
        float4v sa[4];
        #pragma unroll
        for (int ct = 0; ct < 4; ++ct) {
            const unsigned short* krow = ki + bo + (size_t)(s0 + ct * 16 + c) * 64;
            short8v b0 = *(const short8v*)(krow +  0 + g * 8);
            short8v b1 = *(const short8v*)(krow + 32 + g * 8);
            float4v z = {0, 0, 0, 0};
            z = __builtin_amdgcn_mfma_f32_16x16x32_bf16(qf0, b0, z, 0, 0, 0);
            sa[ct] = __builtin_amdgcn_mfma_f32_16x16x32_bf16(qf1, b1, z, 0, 0, 0);
        }

        // ---- issue first half of vT B-frags (latency hides under softmax) ----
        short8v vf0[4];
        #pragma unroll
        for (int ct = 0; ct < 4; ++ct)
            vf0[ct] = *(const short8v*)(vt + bo + (size_t)(ct * 16 + c) * 4096 + s0 + 0 + g * 8);

        // ---- causal mask ----
        if (s0 + 63 > rbase) {
            #pragma unroll
            for (int ct = 0; ct < 4; ++ct)
                #pragma unroll
                for (int j = 0; j < 4; ++j)
                    if (s0 + ct * 16 + c > rbase + g * 4 + j) sa[ct][j] = -3e38f;
        }

        // ---- online softmax (cross-lane sum deferred) ----
        #pragma unroll
        for (int j = 0; j < 4; ++j) {
            float mx = fmaxf(fmaxf(sa[0][j], sa[1][j]), fmaxf(sa[2][j], sa[3][j]));
            #pragma unroll
            for (int sh = 1; sh < 16; sh <<= 1) mx = fmaxf(mx, __shfl_xor(mx, sh, 64));
            const float nm = fmaxf(mrow[j], mx);
            const float al = __expf(mrow[j] - nm);
            mrow[j] = nm;
            float ps = 0.f;
            #pragma unroll
            for (int ct = 0; ct < 4; ++ct) {
                float p = __expf(sa[ct][j] - nm);
                sa[ct][j] = p;
                ps += p;
            }
            lsum[j] = lsum[j] * al + ps;
            #pragma unroll
            for (int ct = 0; ct < 4; ++ct) acc[ct][j] *= al;
        }

        // ---- P (D-layout) -> per-wave LDS -> A-fragment layout ----
        #pragma unroll
        for (int ct = 0; ct < 4; ++ct)
            #pragma unroll
            for (int j = 0; j < 4; ++j)
                Pw[(g * 4 + j) * PLD + ct * 16 + c] = f32_to_bf16(sa[ct][j]);

        // ---- second half of vT B-frags (hides under P roundtrip) ----
        short8v vf1[4];
        #pragma unroll
        for (int ct = 0; ct < 4; ++ct)
            vf1[ct] = *(const short8v*)(vt + bo + (size_t)(ct * 16 + c) * 4096 + s0 + 32 + g * 8);

        short8v pa0 = *(const short8v*)(&Pw[c * PLD +  0 + g * 8]);
        short8v pa1 = *(const short8v*)(&Pw[c * PLD + 32 + g * 8]);

        // ---- O += P V ----
        #pragma unroll
        for (int ct = 0; ct < 4; ++ct)
            acc[ct] = __builtin_amdgcn_mfma_f32_16x16x32_bf16(pa0, vf0[ct], acc[ct], 0, 0, 0);
        #pragma unroll
        for (int ct = 0; ct < 4; ++ct)
            acc[ct] = __builtin_amdgcn_mfma_f32_16x16x32_bf16(pa1, vf1[ct], acc[ct], 0, 0, 0);
    }

    // ---- per-wave: reduce row sums across the 16 c-lanes ----
    #pragma unroll
    for (int j = 0; j < 4; ++j) {
        float l = lsum[j];
        #pragma unroll
        for (int sh = 1; sh < 16; sh <<= 1) l += __shfl_xor(l, sh, 64);
        lsum[j] = l;   // uniform across lanes now
    }

    // ---- cross-slice combine ----
    if (slice > 0) {
        const int sidx = (slice - 1) * 2 + qh;
        #pragma unroll
        for (int ct = 0; ct < 4; ++ct)
            #pragma unroll
            for (int j = 0; j < 4; ++j)
                CombO[sidx][g * 4 + j][ct * 16 + c] = acc[ct][j];
        if (c == 0) {
            #pragma unroll
            for (int j = 0; j < 4; ++j) {
                CombM[sidx][g * 4 + j] = mrow[j];
                CombL[sidx][g * 4 + j] = lsum[j];
            }
        }
    }
    __syncthreads();

    if (slice == 0) {
        float a0[4], as[3][4], linv[4];
        #pragma unroll
        for (int j = 0; j < 4; ++j) {
            const int r = g * 4 + j;
            float M = mrow[j];
            #pragma unroll
            for (int s = 0; s < 3; ++s) M = fmaxf(M, CombM[s * 2 + qh][r]);
            a0[j] = __expf(mrow[j] - M);
            float lt = lsum[j] * a0[j];
            #pragma unroll
            for (int s = 0; s < 3; ++s) {
                as[s][j] = __expf(CombM[s * 2 + qh][r] - M);
                lt += as[s][j] * CombL[s * 2 + qh][r];
            }
            linv[j] = 1.0f / lt;
        }
        #pragma unroll
        for (int ct = 0; ct < 4; ++ct)
            #pragma unroll
            for (int j = 0; j < 4; ++j) {
                const int r = g * 4 + j;
                float o = acc[ct][j] * a0[j];
                #pragma unroll
                for (int s = 0; s < 3; ++s)
                    o += as[s][j] * CombO[s * 2 + qh][r][ct * 16 + c];
                out[bo + (size_t)(rbase + r) * 64 + ct * 16 + c] = o * linv[j];
            }
    }
}

extern "C" void kernel_launch(void* const* d_in, const int* in_sizes, int n_in,
                              void* d_out, int out_size, void* d_ws, size_t ws_size,
                              hipStream_t stream) {
    const float* x  = (const float*)d_in[0];
    const float* Wq = (const float*)d_in[1];
    const float* Wk = (const float*)d_in[2];
    const float* Wv = (const float*)d_in[3];

    unsigned short* Wt = (unsigned short*)d_ws;                        // 384 KiB
    unsigned short* q  = (unsigned short*)((char*)d_ws + (size_t)3 * 65536 * 2);
    unsigned short* k  = q + (size_t)4 * T_LEN * HSZ;
    unsigned short* vT = k + (size_t)4 * T_LEN * HSZ;                  // [B][64][4096]
    float* out = (float*)d_out;

    hipLaunchKernelGGL(wt_kernel,  dim3(768), dim3(256), 0, stream, Wq, Wk, Wv, Wt);
    hipLaunchKernelGGL(qkv_kernel, dim3(1024), dim3(256), 0, stream, x, Wt, q, k, vT);
    hipLaunchKernelGGL(attn_kernel, dim3(512), dim3(512), 0, stream, q, k, vT, out);
}

// Round 10
// 123.049 us; speedup vs baseline: 1.1018x; 1.0050x over previous
//
#include <hip/hip_runtime.h>
#include <stdint.h>

typedef __attribute__((ext_vector_type(8))) short short8v;
typedef __attribute__((ext_vector_type(4))) float float4v;

__device__ __forceinline__ unsigned short f32_to_bf16(float f) {
    union { float f; uint32_t u; } v; v.f = f;
    uint32_t u = v.u;
    u += 0x7FFFu + ((u >> 16) & 1u);
    return (unsigned short)(u >> 16);
}

#define T_LEN 4096
#define C_DIM 1024
#define HSZ 64

// ---------------- kernel 0: W -> Wt (bf16, transposed [192][1024]) ----------------
__global__ void wt_kernel(const float* __restrict__ Wq, const float* __restrict__ Wk,
                          const float* __restrict__ Wv, unsigned short* __restrict__ Wt) {
    int tid = blockIdx.x * blockDim.x + threadIdx.x;   // 0 .. 3*65536-1
    int m   = tid >> 16;
    int rem = tid & 65535;
    int kk  = rem >> 6;
    int col = rem & 63;
    const float* W = (m == 0) ? Wq : ((m == 1) ? Wk : Wv);
    Wt[(size_t)m * 65536 + (size_t)col * 1024 + kk] = f32_to_bf16(W[(size_t)kk * 64 + col]);
}

// ---------------- kernel 1: fused QKV projection (R9, unchanged) ----------------
#define XLD 1032   // 1024 + 8 pad

__global__ __launch_bounds__(256) void qkv_kernel(
    const float* __restrict__ x, const unsigned short* __restrict__ Wt,
    unsigned short* __restrict__ qo, unsigned short* __restrict__ ko,
    unsigned short* __restrict__ vto)
{
    __shared__ __align__(16) unsigned short xs[16 * XLD];
    const int tid = threadIdx.x;
    const int bid = (int)blockIdx.x;
    const int rowidx = (((bid >> 1) & 3) << 8) + ((bid >> 3) << 1) + (bid & 1);
    const int row0 = rowidx * 16;

    #pragma unroll
    for (int i = 0; i < 16; ++i) {
        int f   = i * 256 + tid;           // float4 index, 4096 total
        int row = f >> 8, c4 = f & 255;
        const float4 val = *((const float4*)x + (size_t)(row0 + row) * 256 + c4);
        union { unsigned short s[4]; uint64_t u; } pk;
        pk.s[0] = f32_to_bf16(val.x); pk.s[1] = f32_to_bf16(val.y);
        pk.s[2] = f32_to_bf16(val.z); pk.s[3] = f32_to_bf16(val.w);
        *(uint64_t*)(&xs[row * XLD + c4 * 4]) = pk.u;
    }
    __syncthreads();

    const int wave = tid >> 6, lane = tid & 63;
    const int g = lane >> 4, c = lane & 15;

    float4v acc0 = {0,0,0,0}, acc1 = {0,0,0,0}, acc2 = {0,0,0,0};
    #pragma unroll 4
    for (int ks = 0; ks < 32; ++ks) {
        const int koff = ks * 32 + g * 8;
        short8v a  = *(const short8v*)(&xs[c * XLD + koff]);
        short8v b0 = *(const short8v*)(&Wt[(size_t)((wave*3+0)*16 + c) * 1024 + koff]);
        short8v b1 = *(const short8v*)(&Wt[(size_t)((wave*3+1)*16 + c) * 1024 + koff]);
        short8v b2 = *(const short8v*)(&Wt[(size_t)((wave*3+2)*16 + c) * 1024 + koff]);
        acc0 = __builtin_amdgcn_mfma_f32_16x16x32_bf16(a, b0, acc0, 0, 0, 0);
        acc1 = __builtin_amdgcn_mfma_f32_16x16x32_bf16(a, b1, acc1, 0, 0, 0);
        acc2 = __builtin_amdgcn_mfma_f32_16x16x32_bf16(a, b2, acc2, 0, 0, 0);
    }

    float4v accs[3] = {acc0, acc1, acc2};
    #pragma unroll
    for (int t = 0; t < 3; ++t) {
        int ct = wave * 3 + t;
        int m = ct >> 2, hcol = (ct & 3) * 16 + c;
        if (m == 2) {
            #pragma unroll
            for (int j = 0; j < 4; ++j) {
                int r = row0 + g * 4 + j;
                vto[((size_t)(r >> 12) * 64 + hcol) * 4096 + (r & 4095)] = f32_to_bf16(accs[t][j]);
            }
        } else {
            unsigned short* dst = (m == 0) ? qo : ko;
            float sc = (m == 0) ? 0.125f : 1.0f;   // fold 1/sqrt(64) into q
            #pragma unroll
            for (int j = 0; j < 4; ++j)
                dst[(size_t)(row0 + g * 4 + j) * 64 + hcol] = f32_to_bf16(accs[t][j] * sc);
        }
    }
}

// ---------------- kernel 2: causal flash attention (swapped QK^T) ----------------
// R5/R9 structure (8 waves = 2 qh x 4 slices, direct-global K/vT, XCD pinning),
// but QK^T computed as mfma(K,Q) = S^T so each lane owns ONE q-row (q=rbase+c):
// softmax max = 15 in-lane fmax + 2 shfl_xor; m,l are per-lane scalars.
// PV = mfma(vT,P) accumulating O^T[d][q=c]. All load addresses identical to R9.
#define PLD 72

__global__ __launch_bounds__(512) void attn_kernel(
    const unsigned short* __restrict__ qi, const unsigned short* __restrict__ ki,
    const unsigned short* __restrict__ vt, float* __restrict__ out)
{
    __shared__ __align__(16) unsigned short Ps[8][16 * PLD];  // per-wave P buffer
    __shared__ float CombO[6][16][64];                        // [slot][q-row][d]
    __shared__ float CombM[6][16];
    __shared__ float CombL[6][16];

    const int tid   = threadIdx.x;
    const int wave  = tid >> 6, lane = tid & 63;
    const int qh    = wave & 1, slice = wave >> 1;
    const int g = lane >> 4, c = lane & 15;

    const int bid   = (int)blockIdx.x;
    const int batch = (bid >> 1) & 3;     // XCD pair {2b,2b+1} = batch b
    const int q0    = bid & 1;
    const int m_    = bid >> 3;
    const int mm    = m_ & 31;
    const int qb = q0 ? ((m_ < 32) ? 2 * mm + 1 : 126 - 2 * mm)
                      : ((m_ < 32) ? 2 * mm     : 127 - 2 * mm);

    const int rbase = qb * 32 + qh * 16;
    const size_t bo = (size_t)batch * T_LEN * HSZ;

    short8v qf0 = *(const short8v*)(qi + bo + (size_t)(rbase + c) * 64 +  0 + g * 8);
    short8v qf1 = *(const short8v*)(qi + bo + (size_t)(rbase + c) * 64 + 32 + g * 8);

    float4v acc[4];   // acc[dt][j] = O^T[dt*16+g*4+j][q=rbase+c]
    #pragma unroll
    for (int i2 = 0; i2 < 4; ++i2) acc[i2] = (float4v){0,0,0,0};
    float mrow = -3e38f;   // per-lane: q = rbase+c
    float lsum = 0.f;

    const int nt_w = ((rbase + 15) >> 6) + 1;
    unsigned short* Pw = &Ps[wave][0];

    for (int t = slice; t < nt_w; t += 4) {
        const int s0 = t * 64;

        // ---- S^T = K Q^T : sa[ct][j] = S[q=rbase+c][k=s0+ct*16+g*4+j] ----
        float4v sa[4];
        #pragma unroll
        for (int ct = 0; ct < 4; ++ct) {
            const unsigned short* krow = ki + bo + (size_t)(s0 + ct * 16 + c) * 64;
            short8v b0 = *(const short8v*)(krow +  0 + g * 8);
            short8v b1 = *(const short8v*)(krow + 32 + g * 8);
            float4v z = {0, 0, 0, 0};
            z = __builtin_amdgcn_mfma_f32_16x16x32_bf16(b0, qf0, z, 0, 0, 0);
            sa[ct] = __builtin_amdgcn_mfma_f32_16x16x32_bf16(b1, qf1, z, 0, 0, 0);
        }

        // ---- issue first half of vT A-frags (latency hides under softmax) ----
        short8v vf0[4];
        #pragma unroll
        for (int ct = 0; ct < 4; ++ct)
            vf0[ct] = *(const short8v*)(vt + bo + (size_t)(ct * 16 + c) * 4096 + s0 + 0 + g * 8);

        // ---- causal mask: k = s0+ct*16+g*4+j  vs  q = rbase+c ----
        if (s0 + 63 > rbase) {
            #pragma unroll
            for (int ct = 0; ct < 4; ++ct)
                #pragma unroll
                for (int j = 0; j < 4; ++j)
                    if (s0 + ct * 16 + g * 4 + j > rbase + c) sa[ct][j] = -3e38f;
        }

        // ---- online softmax: lane-local max tree + 2 shfl ----
        float mx01 = fmaxf(fmaxf(sa[0][0], sa[0][1]), fmaxf(sa[0][2], sa[0][3]));
        float mx11 = fmaxf(fmaxf(sa[1][0], sa[1][1]), fmaxf(sa[1][2], sa[1][3]));
        float mx21 = fmaxf(fmaxf(sa[2][0], sa[2][1]), fmaxf(sa[2][2], sa[2][3]));
        float mx31 = fmaxf(fmaxf(sa[3][0], sa[3][1]), fmaxf(sa[3][2], sa[3][3]));
        float mx = fmaxf(fmaxf(mx01, mx11), fmaxf(mx21, mx31));
        mx = fmaxf(mx, __shfl_xor(mx, 16, 64));
        mx = fmaxf(mx, __shfl_xor(mx, 32, 64));
        const float nm = fmaxf(mrow, mx);
        const float al = __expf(mrow - nm);
        mrow = nm;
        float ps = 0.f;
        #pragma unroll
        for (int ct = 0; ct < 4; ++ct)
            #pragma unroll
            for (int j = 0; j < 4; ++j) {
                float p = __expf(sa[ct][j] - nm);
                sa[ct][j] = p;
                ps += p;
            }
        lsum = lsum * al + ps;
        #pragma unroll
        for (int dt = 0; dt < 4; ++dt)
            #pragma unroll
            for (int j = 0; j < 4; ++j) acc[dt][j] *= al;

        // ---- P^T (lane-local rows) -> per-wave LDS: Pw[q=c][k] ----
        #pragma unroll
        for (int ct = 0; ct < 4; ++ct)
            #pragma unroll
            for (int j = 0; j < 4; ++j)
                Pw[c * PLD + ct * 16 + g * 4 + j] = f32_to_bf16(sa[ct][j]);

        // ---- second half of vT A-frags ----
        short8v vf1[4];
        #pragma unroll
        for (int ct = 0; ct < 4; ++ct)
            vf1[ct] = *(const short8v*)(vt + bo + (size_t)(ct * 16 + c) * 4096 + s0 + 32 + g * 8);

        // ---- P B-frags (same addresses as before) ----
        short8v pa0 = *(const short8v*)(&Pw[c * PLD +  0 + g * 8]);
        short8v pa1 = *(const short8v*)(&Pw[c * PLD + 32 + g * 8]);

        // ---- O^T += vT P^T : acc[dt] over d-tile dt ----
        #pragma unroll
        for (int dt = 0; dt < 4; ++dt)
            acc[dt] = __builtin_amdgcn_mfma_f32_16x16x32_bf16(vf0[dt], pa0, acc[dt], 0, 0, 0);
        #pragma unroll
        for (int dt = 0; dt < 4; ++dt)
            acc[dt] = __builtin_amdgcn_mfma_f32_16x16x32_bf16(vf1[dt], pa1, acc[dt], 0, 0, 0);
    }

    // ---- reduce row sum across the 4 g-lanes (same q=c) ----
    lsum += __shfl_xor(lsum, 16, 64);
    lsum += __shfl_xor(lsum, 32, 64);

    // ---- cross-slice combine ----
    if (slice > 0) {
        const int sidx = (slice - 1) * 2 + qh;
        #pragma unroll
        for (int dt = 0; dt < 4; ++dt)
            #pragma unroll
            for (int j = 0; j < 4; ++j)
                CombO[sidx][c][dt * 16 + g * 4 + j] = acc[dt][j];
        if (g == 0) {
            CombM[sidx][c] = mrow;
            CombL[sidx][c] = lsum;
        }
    }
    __syncthreads();

    if (slice == 0) {
        float M = mrow;
        #pragma unroll
        for (int s = 0; s < 3; ++s) M = fmaxf(M, CombM[s * 2 + qh][c]);
        const float a0 = __expf(mrow - M);
        float as[3];
        float lt = lsum * a0;
        #pragma unroll
        for (int s = 0; s < 3; ++s) {
            as[s] = __expf(CombM[s * 2 + qh][c] - M);
            lt += as[s] * CombL[s * 2 + qh][c];
        }
        const float linv = 1.0f / lt;
        #pragma unroll
        for (int dt = 0; dt < 4; ++dt) {
            float4 o;
            float* op = &o.x;
            #pragma unroll
            for (int j = 0; j < 4; ++j) {
                float v = acc[dt][j] * a0;
                #pragma unroll
                for (int s = 0; s < 3; ++s)
                    v += as[s] * CombO[s * 2 + qh][c][dt * 16 + g * 4 + j];
                op[j] = v * linv;
            }
            *(float4*)(out + bo + (size_t)(rbase + c) * 64 + dt * 16 + g * 4) = o;
        }
    }
}

extern "C" void kernel_launch(void* const* d_in, const int* in_sizes, int n_in,
                              void* d_out, int out_size, void* d_ws, size_t ws_size,
                              hipStream_t stream) {
    const float* x  = (const float*)d_in[0];
    const float* Wq = (const float*)d_in[1];
    const float* Wk = (const float*)d_in[2];
    const float* Wv = (const float*)d_in[3];

    unsigned short* Wt = (unsigned short*)d_ws;                        // 384 KiB
    unsigned short* q  = (unsigned short*)((char*)d_ws + (size_t)3 * 65536 * 2);
    unsigned short* k  = q + (size_t)4 * T_LEN * HSZ;
    unsigned short* vT = k + (size_t)4 * T_LEN * HSZ;                  // [B][64][4096]
    float* out = (float*)d_out;

    hipLaunchKernelGGL(wt_kernel,  dim3(768), dim3(256), 0, stream, Wq, Wk, Wv, Wt);
    hipLaunchKernelGGL(qkv_kernel, dim3(1024), dim3(256), 0, stream, x, Wt, q, k, vT);
    hipLaunchKernelGGL(attn_kernel, dim3(512), dim3(512), 0, stream, q, k, vT, out);
}